// Round 2
// baseline (132.822 us; speedup 1.0000x reference)
//
#include <hip/hip_runtime.h>
#include <math.h>

// MultiInterestExtractor — flash-style one-pass masked MLP-attention pooling.
//   N=8192, L=200, D=64, A=5, K=4.
//   One block (4 waves) per sample. Stream h in 64-row chunks:
//     chunk staged to a small LDS tile (reg prefetch issued a phase early),
//     scores -> online-softmax (running m, den) -> PV accumulate, per chunk.
//   h is fetched from HBM exactly once, valid rows only (~211 MB of 419 MB).
//   LDS ~26 KB -> 6 blocks/CU, so barrier stalls in one block are covered by
//   the other 5 (fixes the round-1 stage/compute convoy: 27% HBM duty).

#define LL 200
#define DD 64
#define AA 5
#define KK 4
#define CH 64     // chunk rows
#define HS 65     // LDS row stride in floats: (r*65+d)%32 spreads banks 2-way (free)

__global__ __launch_bounds__(256, 2)
void mie_kernel(const float* __restrict__ h_g,    // [N, L, D]
                const int*   __restrict__ slen_g, // [N]
                const float* __restrict__ W1w,    // [A, D]
                const float* __restrict__ W1b,    // [A]
                const float* __restrict__ W2w,    // [K, A]
                const float* __restrict__ W2b,    // [K]
                float*       __restrict__ out)    // [N, K, D]
{
    __shared__ float h_lds[CH * HS];       // 16.64 KB — current chunk
    __shared__ float part[4][CH][AA];      //  5.12 KB — score partials per d-quarter
    __shared__ float macc[4][KK][DD];      //  4.10 KB — final cross-wave merge
    __shared__ float den_l[4][KK];

    const int n    = blockIdx.x;
    const int t    = threadIdx.x;
    const int lane = t & 63;
    const int wq   = t >> 6;               // wave id
    const int slen = slen_g[n];
    const int nch  = (slen + CH - 1) / CH; // 1..4 chunks, all with >=1 valid row
    const float4* hn4 = (const float4*)(h_g + (size_t)n * LL * DD);
    const int nf4 = slen * (DD / 4);       // only valid rows are ever fetched

    // ---- prologue: stage chunk 0 (zero-fill beyond slen: avoids NaN*0) ----
    float4 rn[4];
    #pragma unroll
    for (int j = 0; j < 4; ++j) {
        int i = j * 256 + t;
        rn[j] = (i < nf4) ? hn4[i] : make_float4(0.f, 0.f, 0.f, 0.f);
    }
    #pragma unroll
    for (int j = 0; j < 4; ++j) {
        int i = j * 256 + t;
        int r = i >> 4, d0 = (i & 15) << 2;
        float* dst = &h_lds[r * HS + d0];
        dst[0] = rn[j].x; dst[1] = rn[j].y; dst[2] = rn[j].z; dst[3] = rn[j].w;
    }
    __syncthreads();

    float m[KK], den[KK], acc[KK];
    #pragma unroll
    for (int k = 0; k < KK; ++k) { m[k] = -INFINITY; den[k] = 0.f; acc[k] = 0.f; }

    for (int c = 0; c < nch; ++c) {
        // ---- issue next chunk's loads early (overlap with compute below) ----
        if (c + 1 < nch) {
            const int base = (c + 1) * (CH * DD / 4);
            #pragma unroll
            for (int j = 0; j < 4; ++j) {
                int i = base + j * 256 + t;
                rn[j] = (i < nf4) ? hn4[i] : make_float4(0.f, 0.f, 0.f, 0.f);
            }
        }

        // ---- score partials: wave wq covers d in [16wq,16wq+16), lane = row.
        //      W1 indices wave-uniform -> scalar loads. ----
        {
            float a0 = 0, a1 = 0, a2 = 0, a3 = 0, a4 = 0;
            const float* hrow = &h_lds[lane * HS + wq * 16];
            const float* w1   = &W1w[wq * 16];
            #pragma unroll
            for (int i = 0; i < 16; ++i) {
                float hv = hrow[i];
                a0 = fmaf(hv, w1[0 * DD + i], a0);
                a1 = fmaf(hv, w1[1 * DD + i], a1);
                a2 = fmaf(hv, w1[2 * DD + i], a2);
                a3 = fmaf(hv, w1[3 * DD + i], a3);
                a4 = fmaf(hv, w1[4 * DD + i], a4);
            }
            float* p5 = &part[wq][lane][0];
            p5[0] = a0; p5[1] = a1; p5[2] = a2; p5[3] = a3; p5[4] = a4;
        }
        __syncthreads();

        // ---- finish scores (all waves redundantly; lane = row) ----
        float p[KK];
        {
            const int rg = c * CH + lane;
            if (rg < slen) {
                float s[AA];
                #pragma unroll
                for (int a = 0; a < AA; ++a)
                    s[a] = tanhf(part[0][lane][a] + part[1][lane][a]
                               + part[2][lane][a] + part[3][lane][a] + W1b[a]);
                #pragma unroll
                for (int k = 0; k < KK; ++k) {
                    float v = W2b[k];
                    #pragma unroll
                    for (int a = 0; a < AA; ++a) v = fmaf(s[a], W2w[k * AA + a], v);
                    p[k] = v;
                }
            } else {
                #pragma unroll
                for (int k = 0; k < KK; ++k) p[k] = -INFINITY;
            }
        }

        // ---- online softmax update (identical across waves: same chunk max) ----
        #pragma unroll
        for (int k = 0; k < KK; ++k) {
            float cm = p[k];
            #pragma unroll
            for (int off = 32; off; off >>= 1) cm = fmaxf(cm, __shfl_xor(cm, off, 64));
            float mn = fmaxf(m[k], cm);
            float f  = expf(m[k] - mn);     // first chunk: exp(-inf)=0, den/acc are 0
            den[k] *= f; acc[k] *= f;
            p[k] = expf(p[k] - mn);         // masked rows -> 0
            m[k] = mn;
        }

        // ---- PV: wave wq owns rows [16wq,16wq+16), lane = d ----
        #pragma unroll 4
        for (int r = 0; r < 16; ++r) {
            const int row = wq * 16 + r;
            float hv = h_lds[row * HS + lane];
            float p0 = __shfl(p[0], row), p1 = __shfl(p[1], row),
                  p2 = __shfl(p[2], row), p3 = __shfl(p[3], row);
            acc[0] = fmaf(p0, hv, acc[0]); den[0] += p0;
            acc[1] = fmaf(p1, hv, acc[1]); den[1] += p1;
            acc[2] = fmaf(p2, hv, acc[2]); den[2] += p2;
            acc[3] = fmaf(p3, hv, acc[3]); den[3] += p3;
        }
        __syncthreads();

        // ---- write prefetched chunk c+1 into LDS ----
        if (c + 1 < nch) {
            #pragma unroll
            for (int j = 0; j < 4; ++j) {
                int i = j * 256 + t;
                int r = i >> 4, d0 = (i & 15) << 2;
                float* dst = &h_lds[r * HS + d0];
                dst[0] = rn[j].x; dst[1] = rn[j].y; dst[2] = rn[j].z; dst[3] = rn[j].w;
            }
            __syncthreads();
        }
    }

    // ---- cross-wave merge: all waves share identical m -> plain sums ----
    #pragma unroll
    for (int k = 0; k < KK; ++k) macc[wq][k][lane] = acc[k];
    if (lane == 0) {
        #pragma unroll
        for (int k = 0; k < KK; ++k) den_l[wq][k] = den[k];
    }
    __syncthreads();
    {
        const int k = t >> 6, dd = t & 63;
        float s  = macc[0][k][dd] + macc[1][k][dd] + macc[2][k][dd] + macc[3][k][dd];
        float dt = den_l[0][k] + den_l[1][k] + den_l[2][k] + den_l[3][k];
        out[(size_t)n * (KK * DD) + t] = s / dt;
    }
}

extern "C" void kernel_launch(void* const* d_in, const int* in_sizes, int n_in,
                              void* d_out, int out_size, void* d_ws, size_t ws_size,
                              hipStream_t stream) {
    const float* h_g  = (const float*)d_in[0];
    const int*   slen = (const int*)  d_in[1];
    const float* W1w  = (const float*)d_in[2];
    const float* W1b  = (const float*)d_in[3];
    const float* W2w  = (const float*)d_in[4];
    const float* W2b  = (const float*)d_in[5];
    float*       outp = (float*)d_out;

    const int N = in_sizes[1];

    mie_kernel<<<dim3(N), dim3(256), 0, stream>>>(h_g, slen, W1w, W1b, W2w, W2b, outp);
}

// Round 3
// 126.722 us; speedup vs baseline: 1.0481x; 1.0481x over previous
//
#include <hip/hip_runtime.h>
#include <math.h>

// MultiInterestExtractor — one WAVE per sample, zero barriers, fixed-shift softmax.
//   N=8192, L=200, D=64, A=5, K=4.
//
// Round-2 post-mortem: the kernel was LDS-instruction-bound (~100 µs/CU of
// ds_bpermute + scalar ds ops), not HBM-bound. This version:
//   * 64-thread blocks (1 wave) -> no __syncthreads (no vmcnt-drain), 9 blocks/CU.
//   * fixed-shift softmax: s <= B_k = |b2_k|+sum|W2[k,:]| (hard bound, tanh in
//     [-1,1]) -> e = exp(s - B_k); identical after normalization; deletes ALL
//     per-chunk max/sum reductions and acc rescales. den reduced once per block.
//   * all LDS ops are b128 with XOR swizzle (slot ^= row&7): staging writes,
//     score reads (lane=row), PV reads (4 rows/instr, lane owns a d-slice).
//     ~65 LDS instrs per chunk-wave vs ~940 cyc x4 waves before.
//   * W1 reads are lane-uniform -> s_load_dwordx4 (scalar pipe, free).
//   * register prefetch of next chunk (16 float4) issued before compute.

#define LL 200
#define DD 64
#define AA 5
#define KK 4
#define CH 64

__global__ __launch_bounds__(64)
void mie_kernel(const float* __restrict__ h_g,    // [N, L, D]
                const int*   __restrict__ slen_g, // [N]
                const float* __restrict__ W1w,    // [A, D]
                const float* __restrict__ W1b,    // [A]
                const float* __restrict__ W2w,    // [K, A]
                const float* __restrict__ W2b,    // [K]
                float*       __restrict__ out)    // [N, K, D]
{
    __shared__ float4 h4[CH * 16];   // 16 KB, XOR-swizzled chunk of h
    __shared__ float4 p4s[CH];       //  1 KB, per-row e[k] (unnormalized p)

    const int n    = blockIdx.x;
    const int lane = threadIdx.x;          // 0..63 — one wave per block
    const int slen = slen_g[n];
    const int nch  = (slen + CH - 1) / CH; // 1..4
    const int nf4  = slen * 16;            // valid float4 count

    const float4* hn4 = (const float4*)(h_g + (size_t)n * (LL * DD));
    const float4* W14 = (const float4*)W1w;     // W14[a*16+i] = W1[a][4i..4i+4)

    // hard per-head score bound: s[k] <= B_k (tanh in [-1,1])
    float Bk[KK];
    #pragma unroll
    for (int k = 0; k < KK; ++k) {
        float b = fabsf(W2b[k]);
        #pragma unroll
        for (int a = 0; a < AA; ++a) b += fabsf(W2w[k * AA + a]);
        Bk[k] = b;
    }

    float4 acc0 = {0,0,0,0}, acc1 = {0,0,0,0}, acc2 = {0,0,0,0}, acc3 = {0,0,0,0};
    float den0 = 0.f, den1 = 0.f, den2 = 0.f, den3 = 0.f;

    // ---- prologue: load + stage chunk 0 (index clamp: OOB lanes re-read the
    //      last valid float4 — finite data, masked to 0 by e=0 later) ----
    float4 rn[16];
    #pragma unroll
    for (int j = 0; j < 16; ++j)
        rn[j] = hn4[min(j * 64 + lane, nf4 - 1)];
    #pragma unroll
    for (int j = 0; j < 16; ++j) {
        int i = j * 64 + lane;
        int r = i >> 4, s = i & 15;
        h4[r * 16 + (s ^ (r & 7))] = rn[j];
    }

    for (int c = 0; c < nch; ++c) {
        // ---- issue next chunk's global loads (hide HBM under compute) ----
        if (c + 1 < nch) {
            const int base = (c + 1) * 1024;
            #pragma unroll
            for (int j = 0; j < 16; ++j)
                rn[j] = hn4[min(base + j * 64 + lane, nf4 - 1)];
        }

        // staged writes -> score reads ordering (same wave; no vmcnt touch)
        asm volatile("s_waitcnt lgkmcnt(0)" ::: "memory");

        // ---- scores: lane = row. W1 is lane-uniform -> scalar loads. ----
        float a0 = W1b[0], a1 = W1b[1], a2 = W1b[2], a3 = W1b[3], a4 = W1b[4];
        #pragma unroll
        for (int i = 0; i < 16; ++i) {
            float4 hv = h4[lane * 16 + (i ^ (lane & 7))];
            float4 w0 = W14[0 * 16 + i], w1 = W14[1 * 16 + i], w2 = W14[2 * 16 + i],
                   w3 = W14[3 * 16 + i], w4 = W14[4 * 16 + i];
            a0 = fmaf(hv.x, w0.x, fmaf(hv.y, w0.y, fmaf(hv.z, w0.z, fmaf(hv.w, w0.w, a0))));
            a1 = fmaf(hv.x, w1.x, fmaf(hv.y, w1.y, fmaf(hv.z, w1.z, fmaf(hv.w, w1.w, a1))));
            a2 = fmaf(hv.x, w2.x, fmaf(hv.y, w2.y, fmaf(hv.z, w2.z, fmaf(hv.w, w2.w, a2))));
            a3 = fmaf(hv.x, w3.x, fmaf(hv.y, w3.y, fmaf(hv.z, w3.z, fmaf(hv.w, w3.w, a3))));
            a4 = fmaf(hv.x, w4.x, fmaf(hv.y, w4.y, fmaf(hv.z, w4.z, fmaf(hv.w, w4.w, a4))));
        }
        const bool valid = (c * CH + lane) < slen;
        const float t0 = tanhf(a0), t1 = tanhf(a1), t2 = tanhf(a2),
                    t3 = tanhf(a3), t4 = tanhf(a4);
        float e[KK];
        #pragma unroll
        for (int k = 0; k < KK; ++k) {
            float s = W2b[k];
            s = fmaf(t0, W2w[k * AA + 0], s);
            s = fmaf(t1, W2w[k * AA + 1], s);
            s = fmaf(t2, W2w[k * AA + 2], s);
            s = fmaf(t3, W2w[k * AA + 3], s);
            s = fmaf(t4, W2w[k * AA + 4], s);
            e[k] = valid ? __expf(s - Bk[k]) : 0.f;   // e in (0, 1]; no reductions
        }
        den0 += e[0]; den1 += e[1]; den2 += e[2]; den3 += e[3];
        p4s[lane] = make_float4(e[0], e[1], e[2], e[3]);

        asm volatile("s_waitcnt lgkmcnt(0)" ::: "memory");

        // ---- PV: 4 rows per instruction; lane owns d-slice (lane&15)*4 of
        //      row-quarter (lane>>4). No rescale (fixed shift). ----
        const int rmax = min(CH, slen - c * CH);
        for (int rr = 0; rr < rmax; rr += 4) {
            const int row = rr + (lane >> 4);
            float4 hv = h4[row * 16 + ((lane & 15) ^ (row & 7))];
            float4 pv = p4s[row];                      // 4-addr broadcast read
            acc0.x = fmaf(pv.x, hv.x, acc0.x); acc0.y = fmaf(pv.x, hv.y, acc0.y);
            acc0.z = fmaf(pv.x, hv.z, acc0.z); acc0.w = fmaf(pv.x, hv.w, acc0.w);
            acc1.x = fmaf(pv.y, hv.x, acc1.x); acc1.y = fmaf(pv.y, hv.y, acc1.y);
            acc1.z = fmaf(pv.y, hv.z, acc1.z); acc1.w = fmaf(pv.y, hv.w, acc1.w);
            acc2.x = fmaf(pv.z, hv.x, acc2.x); acc2.y = fmaf(pv.z, hv.y, acc2.y);
            acc2.z = fmaf(pv.z, hv.z, acc2.z); acc2.w = fmaf(pv.z, hv.w, acc2.w);
            acc3.x = fmaf(pv.w, hv.x, acc3.x); acc3.y = fmaf(pv.w, hv.y, acc3.y);
            acc3.z = fmaf(pv.w, hv.z, acc3.z); acc3.w = fmaf(pv.w, hv.w, acc3.w);
        }

        // ---- write prefetched chunk (wave-local; LDS pipe is in-order) ----
        if (c + 1 < nch) {
            #pragma unroll
            for (int j = 0; j < 16; ++j) {
                int i = j * 64 + lane;
                int r = i >> 4, s = i & 15;
                h4[r * 16 + (s ^ (r & 7))] = rn[j];
            }
        }
    }

    // ---- once per block: reduce acc over row-quarters (lanes ^16, ^32) ----
    #pragma unroll
    for (int off = 16; off <= 32; off <<= 1) {
        acc0.x += __shfl_xor(acc0.x, off, 64); acc0.y += __shfl_xor(acc0.y, off, 64);
        acc0.z += __shfl_xor(acc0.z, off, 64); acc0.w += __shfl_xor(acc0.w, off, 64);
        acc1.x += __shfl_xor(acc1.x, off, 64); acc1.y += __shfl_xor(acc1.y, off, 64);
        acc1.z += __shfl_xor(acc1.z, off, 64); acc1.w += __shfl_xor(acc1.w, off, 64);
        acc2.x += __shfl_xor(acc2.x, off, 64); acc2.y += __shfl_xor(acc2.y, off, 64);
        acc2.z += __shfl_xor(acc2.z, off, 64); acc2.w += __shfl_xor(acc2.w, off, 64);
        acc3.x += __shfl_xor(acc3.x, off, 64); acc3.y += __shfl_xor(acc3.y, off, 64);
        acc3.z += __shfl_xor(acc3.z, off, 64); acc3.w += __shfl_xor(acc3.w, off, 64);
    }
    // den: full 64-lane reduce (each lane held its own rows' e-sums)
    #pragma unroll
    for (int off = 1; off <= 32; off <<= 1) {
        den0 += __shfl_xor(den0, off, 64);
        den1 += __shfl_xor(den1, off, 64);
        den2 += __shfl_xor(den2, off, 64);
        den3 += __shfl_xor(den3, off, 64);
    }

    if (lane < 16) {
        float4* o4 = (float4*)(out + (size_t)n * (KK * DD));
        const float i0 = 1.f / den0, i1 = 1.f / den1, i2 = 1.f / den2, i3 = 1.f / den3;
        o4[0 * 16 + lane] = make_float4(acc0.x * i0, acc0.y * i0, acc0.z * i0, acc0.w * i0);
        o4[1 * 16 + lane] = make_float4(acc1.x * i1, acc1.y * i1, acc1.z * i1, acc1.w * i1);
        o4[2 * 16 + lane] = make_float4(acc2.x * i2, acc2.y * i2, acc2.z * i2, acc2.w * i2);
        o4[3 * 16 + lane] = make_float4(acc3.x * i3, acc3.y * i3, acc3.z * i3, acc3.w * i3);
    }
}

extern "C" void kernel_launch(void* const* d_in, const int* in_sizes, int n_in,
                              void* d_out, int out_size, void* d_ws, size_t ws_size,
                              hipStream_t stream) {
    const float* h_g  = (const float*)d_in[0];
    const int*   slen = (const int*)  d_in[1];
    const float* W1w  = (const float*)d_in[2];
    const float* W1b  = (const float*)d_in[3];
    const float* W2w  = (const float*)d_in[4];
    const float* W2b  = (const float*)d_in[5];
    float*       outp = (float*)d_out;

    const int N = in_sizes[1];

    mie_kernel<<<dim3(N), dim3(64), 0, stream>>>(h_g, slen, W1w, W1b, W2w, W2b, outp);
}

// Round 4
// 92.531 us; speedup vs baseline: 1.4354x; 1.3695x over previous
//
#include <hip/hip_runtime.h>
#include <math.h>

// MultiInterestExtractor — round 4: chain-parallelism experiment.
// Rounds 1-3 (three different structures) all = ~126 us => per-CU time is the
// SUM of per-block serial latencies (no inter-block overlap), not any pipe.
// Fix: one block per (sample, 64-row chunk) -> 4x more independent chains,
// each 4x shorter. Fixed-shift softmax (e = exp(s - B_k), B_k a hard bound
// from |W2|,|b2|, tanh in [-1,1]) makes chunk partials EXACTLY mergeable by
// plain sums: kernel 2 reduces 4 partials (acc[256], den[4]) per sample.

#define LL 200
#define DD 64
#define AA 5
#define KK 4
#define CH 64
#define PSTRIDE 260   // per-partial floats: 256 acc + 4 den

__global__ __launch_bounds__(64)
void mie_part(const float* __restrict__ h_g,    // [N, L, D]
              const int*   __restrict__ slen_g, // [N]
              const float* __restrict__ W1w,    // [A, D]
              const float* __restrict__ W1b,    // [A]
              const float* __restrict__ W2w,    // [K, A]
              const float* __restrict__ W2b,    // [K]
              float*       __restrict__ ws)     // [N*4, 260] partials
{
    __shared__ float4 h4[CH * 16];   // 16 KB, XOR-swizzled chunk
    __shared__ float4 p4s[CH];       //  1 KB, per-row e[k]

    const int bid  = blockIdx.x;
    const int n    = bid >> 2;
    const int c    = bid & 3;
    const int lane = threadIdx.x;            // one wave per block
    const int slen = slen_g[n];
    const int r0   = c * CH;
    float* wsp = ws + (size_t)bid * PSTRIDE;

    if (r0 >= slen) {                        // no valid rows: zero partials
        ((float4*)wsp)[lane] = make_float4(0.f, 0.f, 0.f, 0.f);
        if (lane < 4) wsp[256 + lane] = 0.f;
        return;
    }

    const int nf4 = slen * 16;               // valid float4 count for sample
    const float4* hn4 = (const float4*)(h_g + (size_t)n * (LL * DD));
    const float4* W14 = (const float4*)W1w;

    // ---- load chunk c (clamped: OOB lanes re-read last valid f4 — finite,
    //      later masked by e=0), stage XOR-swizzled ----
    const int base = r0 * 16;
    float4 rn[16];
    #pragma unroll
    for (int j = 0; j < 16; ++j)
        rn[j] = hn4[min(base + j * 64 + lane, nf4 - 1)];
    #pragma unroll
    for (int j = 0; j < 16; ++j) {
        int i = j * 64 + lane;
        int r = i >> 4, s = i & 15;
        h4[r * 16 + (s ^ (r & 7))] = rn[j];
    }

    // hard per-head score bound (tanh in [-1,1]): shared shift across chunks
    float Bk[KK];
    #pragma unroll
    for (int k = 0; k < KK; ++k) {
        float b = fabsf(W2b[k]);
        #pragma unroll
        for (int a = 0; a < AA; ++a) b += fabsf(W2w[k * AA + a]);
        Bk[k] = b;
    }

    asm volatile("s_waitcnt lgkmcnt(0)" ::: "memory");

    // ---- scores: lane = row (relative). W1 lane-uniform -> scalar loads ----
    float a0 = W1b[0], a1 = W1b[1], a2 = W1b[2], a3 = W1b[3], a4 = W1b[4];
    #pragma unroll
    for (int i = 0; i < 16; ++i) {
        float4 hv = h4[lane * 16 + (i ^ (lane & 7))];
        float4 w0 = W14[0 * 16 + i], w1 = W14[1 * 16 + i], w2 = W14[2 * 16 + i],
               w3 = W14[3 * 16 + i], w4 = W14[4 * 16 + i];
        a0 = fmaf(hv.x, w0.x, fmaf(hv.y, w0.y, fmaf(hv.z, w0.z, fmaf(hv.w, w0.w, a0))));
        a1 = fmaf(hv.x, w1.x, fmaf(hv.y, w1.y, fmaf(hv.z, w1.z, fmaf(hv.w, w1.w, a1))));
        a2 = fmaf(hv.x, w2.x, fmaf(hv.y, w2.y, fmaf(hv.z, w2.z, fmaf(hv.w, w2.w, a2))));
        a3 = fmaf(hv.x, w3.x, fmaf(hv.y, w3.y, fmaf(hv.z, w3.z, fmaf(hv.w, w3.w, a3))));
        a4 = fmaf(hv.x, w4.x, fmaf(hv.y, w4.y, fmaf(hv.z, w4.z, fmaf(hv.w, w4.w, a4))));
    }
    const bool valid = (r0 + lane) < slen;
    const float t0 = tanhf(a0), t1 = tanhf(a1), t2 = tanhf(a2),
                t3 = tanhf(a3), t4 = tanhf(a4);
    float e[KK];
    #pragma unroll
    for (int k = 0; k < KK; ++k) {
        float s = W2b[k];
        s = fmaf(t0, W2w[k * AA + 0], s);
        s = fmaf(t1, W2w[k * AA + 1], s);
        s = fmaf(t2, W2w[k * AA + 2], s);
        s = fmaf(t3, W2w[k * AA + 3], s);
        s = fmaf(t4, W2w[k * AA + 4], s);
        e[k] = valid ? __expf(s - Bk[k]) : 0.f;
    }
    float den0 = e[0], den1 = e[1], den2 = e[2], den3 = e[3];
    p4s[lane] = make_float4(e[0], e[1], e[2], e[3]);

    asm volatile("s_waitcnt lgkmcnt(0)" ::: "memory");

    // ---- PV: 4 rows/iter; lane owns d-slice (lane&15)*4, quarter lane>>4 ----
    float4 acc0 = {0,0,0,0}, acc1 = {0,0,0,0}, acc2 = {0,0,0,0}, acc3 = {0,0,0,0};
    const int rmax = min(CH, slen - r0);
    for (int rr = 0; rr < rmax; rr += 4) {
        const int row = rr + (lane >> 4);
        float4 hv = h4[row * 16 + ((lane & 15) ^ (row & 7))];
        float4 pv = p4s[row];
        acc0.x = fmaf(pv.x, hv.x, acc0.x); acc0.y = fmaf(pv.x, hv.y, acc0.y);
        acc0.z = fmaf(pv.x, hv.z, acc0.z); acc0.w = fmaf(pv.x, hv.w, acc0.w);
        acc1.x = fmaf(pv.y, hv.x, acc1.x); acc1.y = fmaf(pv.y, hv.y, acc1.y);
        acc1.z = fmaf(pv.y, hv.z, acc1.z); acc1.w = fmaf(pv.y, hv.w, acc1.w);
        acc2.x = fmaf(pv.z, hv.x, acc2.x); acc2.y = fmaf(pv.z, hv.y, acc2.y);
        acc2.z = fmaf(pv.z, hv.z, acc2.z); acc2.w = fmaf(pv.z, hv.w, acc2.w);
        acc3.x = fmaf(pv.w, hv.x, acc3.x); acc3.y = fmaf(pv.w, hv.y, acc3.y);
        acc3.z = fmaf(pv.w, hv.z, acc3.z); acc3.w = fmaf(pv.w, hv.w, acc3.w);
    }

    // ---- reduce over row-quarters (lanes ^16, ^32); den over all lanes ----
    #pragma unroll
    for (int off = 16; off <= 32; off <<= 1) {
        acc0.x += __shfl_xor(acc0.x, off, 64); acc0.y += __shfl_xor(acc0.y, off, 64);
        acc0.z += __shfl_xor(acc0.z, off, 64); acc0.w += __shfl_xor(acc0.w, off, 64);
        acc1.x += __shfl_xor(acc1.x, off, 64); acc1.y += __shfl_xor(acc1.y, off, 64);
        acc1.z += __shfl_xor(acc1.z, off, 64); acc1.w += __shfl_xor(acc1.w, off, 64);
        acc2.x += __shfl_xor(acc2.x, off, 64); acc2.y += __shfl_xor(acc2.y, off, 64);
        acc2.z += __shfl_xor(acc2.z, off, 64); acc2.w += __shfl_xor(acc2.w, off, 64);
        acc3.x += __shfl_xor(acc3.x, off, 64); acc3.y += __shfl_xor(acc3.y, off, 64);
        acc3.z += __shfl_xor(acc3.z, off, 64); acc3.w += __shfl_xor(acc3.w, off, 64);
    }
    #pragma unroll
    for (int off = 1; off <= 32; off <<= 1) {
        den0 += __shfl_xor(den0, off, 64);
        den1 += __shfl_xor(den1, off, 64);
        den2 += __shfl_xor(den2, off, 64);
        den3 += __shfl_xor(den3, off, 64);
    }

    if (lane < 16) {
        float4* o4 = (float4*)wsp;
        o4[0 * 16 + lane] = acc0;
        o4[1 * 16 + lane] = acc1;
        o4[2 * 16 + lane] = acc2;
        o4[3 * 16 + lane] = acc3;
    }
    if (lane == 0) {
        wsp[256 + 0] = den0; wsp[256 + 1] = den1;
        wsp[256 + 2] = den2; wsp[256 + 3] = den3;
    }
}

__global__ __launch_bounds__(256)
void mie_reduce(const float* __restrict__ ws,   // [N*4, 260]
                float*       __restrict__ out)  // [N, K*D]
{
    __shared__ float dsum[KK];
    const int n = blockIdx.x;
    const int t = threadIdx.x;
    const float* b = ws + (size_t)n * 4 * PSTRIDE;
    float s = b[t] + b[PSTRIDE + t] + b[2 * PSTRIDE + t] + b[3 * PSTRIDE + t];
    if (t < KK)
        dsum[t] = b[256 + t] + b[PSTRIDE + 256 + t]
                + b[2 * PSTRIDE + 256 + t] + b[3 * PSTRIDE + 256 + t];
    __syncthreads();
    out[(size_t)n * 256 + t] = s / dsum[t >> 6];
}

extern "C" void kernel_launch(void* const* d_in, const int* in_sizes, int n_in,
                              void* d_out, int out_size, void* d_ws, size_t ws_size,
                              hipStream_t stream) {
    const float* h_g  = (const float*)d_in[0];
    const int*   slen = (const int*)  d_in[1];
    const float* W1w  = (const float*)d_in[2];
    const float* W1b  = (const float*)d_in[3];
    const float* W2w  = (const float*)d_in[4];
    const float* W2b  = (const float*)d_in[5];
    float*       outp = (float*)d_out;
    float*       wsp  = (float*)d_ws;   // needs N*4*260*4 B = 34.1 MB

    const int N = in_sizes[1];

    mie_part<<<dim3(N * 4), dim3(64), 0, stream>>>(h_g, slen, W1w, W1b, W2w, W2b, wsp);
    mie_reduce<<<dim3(N), dim3(256), 0, stream>>>(wsp, outp);
}

// Round 6
// 83.900 us; speedup vs baseline: 1.5831x; 1.1029x over previous
//
#include <hip/hip_runtime.h>
#include <math.h>

// MultiInterestExtractor — round 6 = round 5 with the bf16 pack fixed
// (ROCm 7.2 has no __floats2bfloat162_rn; hand-rolled RNE bit ops).
// Structure: 1 wave per (sample, 64-row chunk) — 32768 independent chains —
// fixed-shift softmax (e = exp(s - B_k), B_k hard bound, tanh in [-1,1]),
// plain-sum partial merge in kernel 2. LDS halved via bf16 staging:
// 17KB -> 9KB => 9 -> 17 resident chains/CU (the round-4 limiter).

#define LL 200
#define DD 64
#define AA 5
#define KK 4
#define CH 64
#define PSTRIDE 260   // per-partial floats: 256 acc + 4 den

__device__ __forceinline__ unsigned bf16_rne(float f) {   // top-16 bits, RNE
    unsigned u = __float_as_uint(f);
    return (u + 0x7FFFu + ((u >> 16) & 1u)) >> 16;        // finite inputs only
}
__device__ __forceinline__ unsigned pk2(float lo, float hi) {
    return bf16_rne(lo) | (bf16_rne(hi) << 16);
}
__device__ __forceinline__ float lo16(unsigned u) { return __uint_as_float(u << 16); }
__device__ __forceinline__ float hi16(unsigned u) { return __uint_as_float(u & 0xFFFF0000u); }

__device__ __forceinline__ float fast_tanh(float x) {
    float e = __expf(2.f * x);                         // +inf for large x -> ok
    return 1.f - 2.f * __builtin_amdgcn_rcpf(e + 1.f); // saturates to +/-1
}

__global__ __launch_bounds__(64, 4)   // cap VGPR<=128: 4 waves/SIMD possible
void mie_part(const float* __restrict__ h_g,    // [N, L, D]
              const int*   __restrict__ slen_g, // [N]
              const float* __restrict__ W1w,    // [A, D]
              const float* __restrict__ W1b,    // [A]
              const float* __restrict__ W2w,    // [K, A]
              const float* __restrict__ W2b,    // [K]
              float*       __restrict__ ws)     // [N*4, 260] partials
{
    __shared__ uint2  hb[CH * 16];   // 8 KB: row-slot = 4 bf16 (8 B), XOR-swizzled
    __shared__ float4 p4s[CH];       // 1 KB: per-row e[k]

    const int bid  = blockIdx.x;
    const int n    = bid >> 2;
    const int c    = bid & 3;
    const int lane = threadIdx.x;            // one wave per block
    const int slen = slen_g[n];
    const int r0   = c * CH;
    float* wsp = ws + (size_t)bid * PSTRIDE;

    if (r0 >= slen) {                        // no valid rows: zero partials
        ((float4*)wsp)[lane] = make_float4(0.f, 0.f, 0.f, 0.f);
        if (lane < 4) wsp[256 + lane] = 0.f;
        return;
    }

    const int nf4 = slen * 16;
    const float4* hn4 = (const float4*)(h_g + (size_t)n * (LL * DD));
    const float4* W14 = (const float4*)W1w;

    // ---- load chunk (clamped OOB -> last valid f4, finite; masked by e=0),
    //      stage as bf16 pairs, XOR-swizzled at 8B slot granularity ----
    const int base = r0 * 16;
    float4 rn[16];
    #pragma unroll
    for (int j = 0; j < 16; ++j)
        rn[j] = hn4[min(base + j * 64 + lane, nf4 - 1)];
    #pragma unroll
    for (int j = 0; j < 16; ++j) {
        int i = j * 64 + lane;
        int r = i >> 4, s = i & 15;
        hb[r * 16 + (s ^ (r & 15))] = make_uint2(pk2(rn[j].x, rn[j].y),
                                                 pk2(rn[j].z, rn[j].w));
    }

    // hard per-head score bound (tanh in [-1,1]): shared shift across chunks
    float Bk[KK];
    #pragma unroll
    for (int k = 0; k < KK; ++k) {
        float b = fabsf(W2b[k]);
        #pragma unroll
        for (int a = 0; a < AA; ++a) b += fabsf(W2w[k * AA + a]);
        Bk[k] = b;
    }

    asm volatile("s_waitcnt lgkmcnt(0)" ::: "memory");

    // ---- scores: lane = row. W1 lane-uniform -> scalar loads. ----
    float a0 = W1b[0], a1 = W1b[1], a2 = W1b[2], a3 = W1b[3], a4 = W1b[4];
    #pragma unroll
    for (int i = 0; i < 16; ++i) {
        uint2 q = hb[lane * 16 + (i ^ (lane & 15))];
        float hx = lo16(q.x), hy = hi16(q.x), hz = lo16(q.y), hw = hi16(q.y);
        float4 w0 = W14[0 * 16 + i], w1 = W14[1 * 16 + i], w2 = W14[2 * 16 + i],
               w3 = W14[3 * 16 + i], w4 = W14[4 * 16 + i];
        a0 = fmaf(hx, w0.x, fmaf(hy, w0.y, fmaf(hz, w0.z, fmaf(hw, w0.w, a0))));
        a1 = fmaf(hx, w1.x, fmaf(hy, w1.y, fmaf(hz, w1.z, fmaf(hw, w1.w, a1))));
        a2 = fmaf(hx, w2.x, fmaf(hy, w2.y, fmaf(hz, w2.z, fmaf(hw, w2.w, a2))));
        a3 = fmaf(hx, w3.x, fmaf(hy, w3.y, fmaf(hz, w3.z, fmaf(hw, w3.w, a3))));
        a4 = fmaf(hx, w4.x, fmaf(hy, w4.y, fmaf(hz, w4.z, fmaf(hw, w4.w, a4))));
    }
    const bool valid = (r0 + lane) < slen;
    const float t0 = fast_tanh(a0), t1 = fast_tanh(a1), t2 = fast_tanh(a2),
                t3 = fast_tanh(a3), t4 = fast_tanh(a4);
    float e[KK];
    #pragma unroll
    for (int k = 0; k < KK; ++k) {
        float s = W2b[k];
        s = fmaf(t0, W2w[k * AA + 0], s);
        s = fmaf(t1, W2w[k * AA + 1], s);
        s = fmaf(t2, W2w[k * AA + 2], s);
        s = fmaf(t3, W2w[k * AA + 3], s);
        s = fmaf(t4, W2w[k * AA + 4], s);
        e[k] = valid ? __expf(s - Bk[k]) : 0.f;   // e in (0,1]; no reductions
    }
    float den0 = e[0], den1 = e[1], den2 = e[2], den3 = e[3];
    p4s[lane] = make_float4(e[0], e[1], e[2], e[3]);

    asm volatile("s_waitcnt lgkmcnt(0)" ::: "memory");

    // ---- PV: 4 rows/iter; lane owns d-slice (lane&15)*4, quarter lane>>4 ----
    float4 acc0 = {0,0,0,0}, acc1 = {0,0,0,0}, acc2 = {0,0,0,0}, acc3 = {0,0,0,0};
    const int rmax = min(CH, slen - r0);
    for (int rr = 0; rr < rmax; rr += 4) {
        const int row = rr + (lane >> 4);
        uint2 q = hb[row * 16 + ((lane & 15) ^ (row & 15))];
        float hx = lo16(q.x), hy = hi16(q.x), hz = lo16(q.y), hw = hi16(q.y);
        float4 pv = p4s[row];          // rows beyond slen carry e=0 -> no-op
        acc0.x = fmaf(pv.x, hx, acc0.x); acc0.y = fmaf(pv.x, hy, acc0.y);
        acc0.z = fmaf(pv.x, hz, acc0.z); acc0.w = fmaf(pv.x, hw, acc0.w);
        acc1.x = fmaf(pv.y, hx, acc1.x); acc1.y = fmaf(pv.y, hy, acc1.y);
        acc1.z = fmaf(pv.y, hz, acc1.z); acc1.w = fmaf(pv.y, hw, acc1.w);
        acc2.x = fmaf(pv.z, hx, acc2.x); acc2.y = fmaf(pv.z, hy, acc2.y);
        acc2.z = fmaf(pv.z, hz, acc2.z); acc2.w = fmaf(pv.z, hw, acc2.w);
        acc3.x = fmaf(pv.w, hx, acc3.x); acc3.y = fmaf(pv.w, hy, acc3.y);
        acc3.z = fmaf(pv.w, hz, acc3.z); acc3.w = fmaf(pv.w, hw, acc3.w);
    }

    // ---- reduce over row-quarters (lanes ^16, ^32); den over all lanes ----
    #pragma unroll
    for (int off = 16; off <= 32; off <<= 1) {
        acc0.x += __shfl_xor(acc0.x, off, 64); acc0.y += __shfl_xor(acc0.y, off, 64);
        acc0.z += __shfl_xor(acc0.z, off, 64); acc0.w += __shfl_xor(acc0.w, off, 64);
        acc1.x += __shfl_xor(acc1.x, off, 64); acc1.y += __shfl_xor(acc1.y, off, 64);
        acc1.z += __shfl_xor(acc1.z, off, 64); acc1.w += __shfl_xor(acc1.w, off, 64);
        acc2.x += __shfl_xor(acc2.x, off, 64); acc2.y += __shfl_xor(acc2.y, off, 64);
        acc2.z += __shfl_xor(acc2.z, off, 64); acc2.w += __shfl_xor(acc2.w, off, 64);
        acc3.x += __shfl_xor(acc3.x, off, 64); acc3.y += __shfl_xor(acc3.y, off, 64);
        acc3.z += __shfl_xor(acc3.z, off, 64); acc3.w += __shfl_xor(acc3.w, off, 64);
    }
    #pragma unroll
    for (int off = 1; off <= 32; off <<= 1) {
        den0 += __shfl_xor(den0, off, 64);
        den1 += __shfl_xor(den1, off, 64);
        den2 += __shfl_xor(den2, off, 64);
        den3 += __shfl_xor(den3, off, 64);
    }

    if (lane < 16) {
        float4* o4 = (float4*)wsp;
        o4[0 * 16 + lane] = acc0;
        o4[1 * 16 + lane] = acc1;
        o4[2 * 16 + lane] = acc2;
        o4[3 * 16 + lane] = acc3;
    }
    if (lane == 0) {
        wsp[256 + 0] = den0; wsp[256 + 1] = den1;
        wsp[256 + 2] = den2; wsp[256 + 3] = den3;
    }
}

__global__ __launch_bounds__(256)
void mie_reduce(const float* __restrict__ ws,   // [N*4, 260]
                float*       __restrict__ out)  // [N, K*D]
{
    __shared__ float dsum[KK];
    const int n = blockIdx.x;
    const int t = threadIdx.x;
    const float* b = ws + (size_t)n * 4 * PSTRIDE;
    float s = b[t] + b[PSTRIDE + t] + b[2 * PSTRIDE + t] + b[3 * PSTRIDE + t];
    if (t < KK)
        dsum[t] = b[256 + t] + b[PSTRIDE + 256 + t]
                + b[2 * PSTRIDE + 256 + t] + b[3 * PSTRIDE + 256 + t];
    __syncthreads();
    out[(size_t)n * 256 + t] = s / dsum[t >> 6];
}

extern "C" void kernel_launch(void* const* d_in, const int* in_sizes, int n_in,
                              void* d_out, int out_size, void* d_ws, size_t ws_size,
                              hipStream_t stream) {
    const float* h_g  = (const float*)d_in[0];
    const int*   slen = (const int*)  d_in[1];
    const float* W1w  = (const float*)d_in[2];
    const float* W1b  = (const float*)d_in[3];
    const float* W2w  = (const float*)d_in[4];
    const float* W2b  = (const float*)d_in[5];
    float*       outp = (float*)d_out;
    float*       wsp  = (float*)d_ws;   // N*4*260*4 B = 34.1 MB

    const int N = in_sizes[1];

    mie_part<<<dim3(N * 4), dim3(64), 0, stream>>>(h_g, slen, W1w, W1b, W2w, W2b, wsp);
    mie_reduce<<<dim3(N), dim3(256), 0, stream>>>(wsp, outp);
}

// Round 7
// 70.223 us; speedup vs baseline: 1.8914x; 1.1948x over previous
//
#include <hip/hip_runtime.h>
#include <math.h>

// MultiInterestExtractor — round 7: FUSED single kernel.
// 1 block = 1 sample (256 thr = 4 waves). Wave w owns rows {l : l%4==w}
// (<=50 rows) -> all waves finish together (no skew), every wave active for
// every sample. Fixed-shift softmax (e = exp(s - B_k), B_k hard bound from
// |W2|,|b2|, tanh in [-1,1]) -> wave partials merge by PLAIN SUM in LDS after
// one barrier. Kills: ws round-trip (68 MB), reduce kernel, 15.7k trivial
// dispatches, bf16 pack/unpack (~400 VALU/blk), shuffle reductions.
// LDS: per-wave h region 52 rows x 68 floats (272 B row stride -> score,
// PV, staging all at the 8-cycle bank floor, zero conflicts). ~60 KB total
// -> 2 blocks/CU; merge reuses the wave's own dead h region.

#define LL 200
#define DD 64
#define AA 5
#define KK 4
#define RSTRIDE 68        // floats per LDS row (64 + 4 pad)
#define WREG    3584      // floats per wave region (52 rows x 68 = 3536, pad)

__device__ __forceinline__ float fast_tanh(float x) {
    float e = __expf(2.f * x);                          // +inf for large x ok
    return 1.f - 2.f * __builtin_amdgcn_rcpf(e + 1.f);  // saturates to +/-1
}

__global__ __launch_bounds__(256, 2)
void mie_fused(const float* __restrict__ h_g,    // [N, L, D]
               const int*   __restrict__ slen_g, // [N]
               const float* __restrict__ W1w,    // [A, D]
               const float* __restrict__ W1b,    // [A]
               const float* __restrict__ W2w,    // [K, A]
               const float* __restrict__ W2b,    // [K]
               float*       __restrict__ out)    // [N, K, D]
{
    __shared__ __align__(16) float hbuf[4 * WREG];     // 57344 B
    __shared__ __align__(16) float4 p4s[4][52];        //  3328 B
    __shared__ __align__(16) float den_s[4][4][KK];    //   256 B  [wave][rq][k]

    const int n    = blockIdx.x;
    const int t    = threadIdx.x;
    const int w    = t >> 6;                 // wave id = row phase
    const int lane = t & 63;
    const int slen = slen_g[n];

    // rows of this wave: global rows w, w+4, ... < slen  (1..50 rows; wave w
    // idle only when slen <= w, i.e. slen < 4)
    const int nrows = (slen > w) ? ((slen - w + 3) >> 2) : 0;
    float* hbw = &hbuf[w * WREG];

    if (nrows == 0) {
        // zero own merge region (4 KB) + den entries, then wait at barrier
        float4 z = {0.f, 0.f, 0.f, 0.f};
        #pragma unroll
        for (int q = 0; q < 4; ++q)
            *(float4*)&hbw[q * 256 + lane * 4] = z;
        if (lane < 4) *(float4*)&den_s[w][lane][0] = z;
    } else {
        const int nf4 = slen * 16;
        const float4* hn4 = (const float4*)(h_g + (size_t)n * (LL * DD));

        // ---- stage: 13 clamped float4 loads (rows 0..51 local, row-major),
        //      all issued before first use; ds_write to padded layout ----
        float4 rn[13];
        #pragma unroll
        for (int j = 0; j < 13; ++j) {
            int i = j * 64 + lane;
            int r = i >> 4, c = i & 15;               // local row, f4 col
            int idx = min((r * 4 + w) * 16 + c, nf4 - 1);  // clamp: L2 dup, finite
            rn[j] = hn4[idx];
        }
        #pragma unroll
        for (int j = 0; j < 13; ++j) {
            int i = j * 64 + lane;
            int r = i >> 4, c = i & 15;
            *(float4*)&hbw[r * RSTRIDE + c * 4] = rn[j];   // (r+c)%8 bank groups: floor
        }

        // hard per-head score bound (tanh in [-1,1]): same shift for all waves
        float Bk[KK];
        #pragma unroll
        for (int k = 0; k < KK; ++k) {
            float b = fabsf(W2b[k]);
            #pragma unroll
            for (int a = 0; a < AA; ++a) b += fabsf(W2w[k * AA + a]);
            Bk[k] = b;
        }

        asm volatile("s_waitcnt lgkmcnt(0)" ::: "memory");

        // ---- scores: lane = local row. W1 lane-uniform -> scalar loads ----
        const float4* W14 = (const float4*)W1w;
        const int rl = min(lane, 51);                  // keep reads in-region
        float a0 = W1b[0], a1 = W1b[1], a2 = W1b[2], a3 = W1b[3], a4 = W1b[4];
        #pragma unroll
        for (int i = 0; i < 16; ++i) {
            float4 hv = *(const float4*)&hbw[rl * RSTRIDE + i * 4];
            float4 w0 = W14[0*16+i], w1 = W14[1*16+i], w2 = W14[2*16+i],
                   w3 = W14[3*16+i], w4 = W14[4*16+i];
            a0 = fmaf(hv.x, w0.x, fmaf(hv.y, w0.y, fmaf(hv.z, w0.z, fmaf(hv.w, w0.w, a0))));
            a1 = fmaf(hv.x, w1.x, fmaf(hv.y, w1.y, fmaf(hv.z, w1.z, fmaf(hv.w, w1.w, a1))));
            a2 = fmaf(hv.x, w2.x, fmaf(hv.y, w2.y, fmaf(hv.z, w2.z, fmaf(hv.w, w2.w, a2))));
            a3 = fmaf(hv.x, w3.x, fmaf(hv.y, w3.y, fmaf(hv.z, w3.z, fmaf(hv.w, w3.w, a3))));
            a4 = fmaf(hv.x, w4.x, fmaf(hv.y, w4.y, fmaf(hv.z, w4.z, fmaf(hv.w, w4.w, a4))));
        }
        const bool vrow = lane < nrows;
        const float t0 = fast_tanh(a0), t1 = fast_tanh(a1), t2 = fast_tanh(a2),
                    t3 = fast_tanh(a3), t4 = fast_tanh(a4);
        float e[KK];
        #pragma unroll
        for (int k = 0; k < KK; ++k) {
            float s = W2b[k];
            s = fmaf(t0, W2w[k*AA+0], s);
            s = fmaf(t1, W2w[k*AA+1], s);
            s = fmaf(t2, W2w[k*AA+2], s);
            s = fmaf(t3, W2w[k*AA+3], s);
            s = fmaf(t4, W2w[k*AA+4], s);
            e[k] = vrow ? __expf(s - Bk[k]) : 0.f;     // e in (0,1]
        }
        if (lane < 52)
            p4s[w][lane] = make_float4(e[0], e[1], e[2], e[3]);  // rows>=nrows: 0

        asm volatile("s_waitcnt lgkmcnt(0)" ::: "memory");

        // ---- PV: lane = (rq = lane>>4 row-group, dc = lane&15 f4-col) ----
        const int rq = lane >> 4, dc = lane & 15;
        float4 acc0 = {0,0,0,0}, acc1 = {0,0,0,0}, acc2 = {0,0,0,0}, acc3 = {0,0,0,0};
        float dn0 = 0.f, dn1 = 0.f, dn2 = 0.f, dn3 = 0.f;
        const int gmax = (nrows + 3) >> 2;             // <= 13
        for (int g = 0; g < gmax; ++g) {
            const int row = g * 4 + rq;                // <= 51; pad rows have e=0
            float4 hv = *(const float4*)&hbw[row * RSTRIDE + dc * 4];
            float4 pv = p4s[w][row];
            acc0.x = fmaf(pv.x, hv.x, acc0.x); acc0.y = fmaf(pv.x, hv.y, acc0.y);
            acc0.z = fmaf(pv.x, hv.z, acc0.z); acc0.w = fmaf(pv.x, hv.w, acc0.w);
            acc1.x = fmaf(pv.y, hv.x, acc1.x); acc1.y = fmaf(pv.y, hv.y, acc1.y);
            acc1.z = fmaf(pv.y, hv.z, acc1.z); acc1.w = fmaf(pv.y, hv.w, acc1.w);
            acc2.x = fmaf(pv.z, hv.x, acc2.x); acc2.y = fmaf(pv.z, hv.y, acc2.y);
            acc2.z = fmaf(pv.z, hv.z, acc2.z); acc2.w = fmaf(pv.z, hv.w, acc2.w);
            acc3.x = fmaf(pv.w, hv.x, acc3.x); acc3.y = fmaf(pv.w, hv.y, acc3.y);
            acc3.z = fmaf(pv.w, hv.z, acc3.z); acc3.w = fmaf(pv.w, hv.w, acc3.w);
            dn0 += pv.x; dn1 += pv.y; dn2 += pv.z; dn3 += pv.w;
        }

        // ---- merge: write rq-partials into OWN dead h region; no shuffles ----
        // region layout: float idx = rq*256 + k*64 + d   (d = dc*4+f)
        *(float4*)&hbw[rq * 256 + 0 * 64 + dc * 4] = acc0;
        *(float4*)&hbw[rq * 256 + 1 * 64 + dc * 4] = acc1;
        *(float4*)&hbw[rq * 256 + 2 * 64 + dc * 4] = acc2;
        *(float4*)&hbw[rq * 256 + 3 * 64 + dc * 4] = acc3;
        if (dc == 0)
            *(float4*)&den_s[w][rq][0] = make_float4(dn0, dn1, dn2, dn3);
    }

    __syncthreads();

    // ---- epilogue: sum 16 partials (4 waves x 4 rq) per output element ----
    {
        float s = 0.f;
        #pragma unroll
        for (int i = 0; i < 16; ++i)
            s += hbuf[(i >> 2) * WREG + (i & 3) * 256 + t];   // lanes consecutive: free
        const int k = t >> 6;
        float den = 0.f;
        #pragma unroll
        for (int i = 0; i < 16; ++i)
            den += den_s[i >> 2][i & 3][k];                   // broadcast reads
        out[(size_t)n * (KK * DD) + t] = s / den;             // den>0 (slen>=1)
    }
}

extern "C" void kernel_launch(void* const* d_in, const int* in_sizes, int n_in,
                              void* d_out, int out_size, void* d_ws, size_t ws_size,
                              hipStream_t stream) {
    const float* h_g  = (const float*)d_in[0];
    const int*   slen = (const int*)  d_in[1];
    const float* W1w  = (const float*)d_in[2];
    const float* W1b  = (const float*)d_in[3];
    const float* W2w  = (const float*)d_in[4];
    const float* W2b  = (const float*)d_in[5];
    float*       outp = (float*)d_out;

    const int N = in_sizes[1];

    mie_fused<<<dim3(N), dim3(256), 0, stream>>>(h_g, slen, W1w, W1b, W2w, W2b, outp);
}

// Round 8
// 60.852 us; speedup vs baseline: 2.1827x; 1.1540x over previous
//
#include <hip/hip_runtime.h>
#include <math.h>

// MultiInterestExtractor — round 8: fused kernel (round 7) + bf16 LDS staging.
// Round-7 arithmetic: ~91 LDS ops/wave, mostly b128 (~12cy) => ~50us/CU LDS
// demand at only 8 waves/CU resident (60KB LDS/block). bf16 staging halves
// both: b64 ops (~5.5cy) and footprint 60->30KB => 4 blocks/CU = 16 waves/CU
// at __launch_bounds__(256,4). bf16-h numerics validated in round 6 (0.0156).
// Layout: per-wave region, 52 rows x 16 uint2 slots (4 bf16/slot), XOR swizzle
// slot = c ^ (r&15): stage/score/PV all at the wave64-b64 bank floor.
// Fixed-shift softmax (e = exp(s - B_k), B_k hard bound, tanh in [-1,1]) ->
// wave/quarter partials merge by plain sum in the wave's dead h region.

#define LL 200
#define DD 64
#define AA 5
#define KK 4
#define WU2  832           // uint2 per wave region (52 rows x 16 slots)
#define FREG (WU2 * 2)     // floats per region when reused as merge scratch

__device__ __forceinline__ unsigned bf16_rne(float f) {   // finite inputs
    unsigned u = __float_as_uint(f);
    return (u + 0x7FFFu + ((u >> 16) & 1u)) >> 16;
}
__device__ __forceinline__ unsigned pk2(float lo, float hi) {
    return bf16_rne(lo) | (bf16_rne(hi) << 16);
}
__device__ __forceinline__ float lo16(unsigned u) { return __uint_as_float(u << 16); }
__device__ __forceinline__ float hi16(unsigned u) { return __uint_as_float(u & 0xFFFF0000u); }

__device__ __forceinline__ float fast_tanh(float x) {
    float e = __expf(2.f * x);                          // +inf for large x ok
    return 1.f - 2.f * __builtin_amdgcn_rcpf(e + 1.f);  // saturates to +/-1
}

__global__ __launch_bounds__(256, 4)
void mie_fused(const float* __restrict__ h_g,    // [N, L, D]
               const int*   __restrict__ slen_g, // [N]
               const float* __restrict__ W1w,    // [A, D]
               const float* __restrict__ W1b,    // [A]
               const float* __restrict__ W2w,    // [K, A]
               const float* __restrict__ W2b,    // [K]
               float*       __restrict__ out)    // [N, K, D]
{
    __shared__ uint2  hbuf[4 * WU2];        // 26624 B (bf16 h, 4 wave regions)
    __shared__ float4 p4s[4][52];           //  3328 B per-row e[k]
    __shared__ float  den_s[4][4][KK];      //   256 B [wave][rq][k]

    const int n    = blockIdx.x;
    const int t    = threadIdx.x;
    const int w    = t >> 6;                // wave id = row phase (l % 4 == w)
    const int lane = t & 63;
    const int slen = slen_g[n];

    const int nrows = (slen > w) ? ((slen - w + 3) >> 2) : 0;   // <= 50
    uint2* hbw     = &hbuf[w * WU2];
    float* fregion = (float*)hbw;           // merge scratch (h dead by then)

    if (nrows == 0) {                       // only when slen < 4
        float4 z = {0.f, 0.f, 0.f, 0.f};
        #pragma unroll
        for (int q = 0; q < 4; ++q)
            *(float4*)&fregion[q * 256 + lane * 4] = z;
        if (lane < 4) *(float4*)&den_s[w][lane][0] = z;
    } else {
        const int nf4 = slen * 16;
        const float4* hn4 = (const float4*)(h_g + (size_t)n * (LL * DD));

        // ---- stage: 13 clamped float4 loads (all issued up front), packed
        //      to bf16 pairs, XOR-swizzled uint2 writes ----
        float4 rn[13];
        #pragma unroll
        for (int j = 0; j < 13; ++j) {
            int i = j * 64 + lane;
            int r = i >> 4, c = i & 15;                    // local row, f4 col
            rn[j] = hn4[min((r * 4 + w) * 16 + c, nf4 - 1)];  // clamp: L2 dup
        }
        #pragma unroll
        for (int j = 0; j < 13; ++j) {
            int i = j * 64 + lane;
            int r = i >> 4, c = i & 15;
            hbw[r * 16 + (c ^ (r & 15))] =
                make_uint2(pk2(rn[j].x, rn[j].y), pk2(rn[j].z, rn[j].w));
        }

        // hard per-head score bound (tanh in [-1,1]): same shift all chunks
        float Bk[KK];
        #pragma unroll
        for (int k = 0; k < KK; ++k) {
            float b = fabsf(W2b[k]);
            #pragma unroll
            for (int a = 0; a < AA; ++a) b += fabsf(W2w[k * AA + a]);
            Bk[k] = b;
        }

        asm volatile("s_waitcnt lgkmcnt(0)" ::: "memory");

        // ---- scores: lane = local row; W1 lane-uniform -> scalar loads ----
        const float4* W14 = (const float4*)W1w;
        const int rl = min(lane, 51);                      // stay in-region
        float a0 = W1b[0], a1 = W1b[1], a2 = W1b[2], a3 = W1b[3], a4 = W1b[4];
        #pragma unroll
        for (int i = 0; i < 16; ++i) {
            uint2 q = hbw[rl * 16 + (i ^ (rl & 15))];
            float hx = lo16(q.x), hy = hi16(q.x), hz = lo16(q.y), hw = hi16(q.y);
            float4 w0 = W14[0*16+i], w1 = W14[1*16+i], w2 = W14[2*16+i],
                   w3 = W14[3*16+i], w4 = W14[4*16+i];
            a0 = fmaf(hx, w0.x, fmaf(hy, w0.y, fmaf(hz, w0.z, fmaf(hw, w0.w, a0))));
            a1 = fmaf(hx, w1.x, fmaf(hy, w1.y, fmaf(hz, w1.z, fmaf(hw, w1.w, a1))));
            a2 = fmaf(hx, w2.x, fmaf(hy, w2.y, fmaf(hz, w2.z, fmaf(hw, w2.w, a2))));
            a3 = fmaf(hx, w3.x, fmaf(hy, w3.y, fmaf(hz, w3.z, fmaf(hw, w3.w, a3))));
            a4 = fmaf(hx, w4.x, fmaf(hy, w4.y, fmaf(hz, w4.z, fmaf(hw, w4.w, a4))));
        }
        const bool vrow = lane < nrows;
        const float t0 = fast_tanh(a0), t1 = fast_tanh(a1), t2 = fast_tanh(a2),
                    t3 = fast_tanh(a3), t4 = fast_tanh(a4);
        float e[KK];
        #pragma unroll
        for (int k = 0; k < KK; ++k) {
            float s = W2b[k];
            s = fmaf(t0, W2w[k*AA+0], s);
            s = fmaf(t1, W2w[k*AA+1], s);
            s = fmaf(t2, W2w[k*AA+2], s);
            s = fmaf(t3, W2w[k*AA+3], s);
            s = fmaf(t4, W2w[k*AA+4], s);
            e[k] = vrow ? __expf(s - Bk[k]) : 0.f;         // e in (0,1]
        }
        if (lane < 52)
            p4s[w][lane] = make_float4(e[0], e[1], e[2], e[3]); // pads: e=0

        asm volatile("s_waitcnt lgkmcnt(0)" ::: "memory");

        // ---- PV: lane = (rq = lane>>4 row-in-group, dc = lane&15 slot) ----
        const int rq = lane >> 4, dc = lane & 15;
        float4 acc0 = {0,0,0,0}, acc1 = {0,0,0,0}, acc2 = {0,0,0,0}, acc3 = {0,0,0,0};
        float dn0 = 0.f, dn1 = 0.f, dn2 = 0.f, dn3 = 0.f;
        const int gmax = (nrows + 3) >> 2;                 // <= 13
        for (int g = 0; g < gmax; ++g) {
            const int row = g * 4 + rq;                    // <= 51; pads e=0
            uint2 q = hbw[row * 16 + (dc ^ (row & 15))];
            float hx = lo16(q.x), hy = hi16(q.x), hz = lo16(q.y), hw = hi16(q.y);
            float4 pv = p4s[w][row];
            acc0.x = fmaf(pv.x, hx, acc0.x); acc0.y = fmaf(pv.x, hy, acc0.y);
            acc0.z = fmaf(pv.x, hz, acc0.z); acc0.w = fmaf(pv.x, hw, acc0.w);
            acc1.x = fmaf(pv.y, hx, acc1.x); acc1.y = fmaf(pv.y, hy, acc1.y);
            acc1.z = fmaf(pv.y, hz, acc1.z); acc1.w = fmaf(pv.y, hw, acc1.w);
            acc2.x = fmaf(pv.z, hx, acc2.x); acc2.y = fmaf(pv.z, hy, acc2.y);
            acc2.z = fmaf(pv.z, hz, acc2.z); acc2.w = fmaf(pv.z, hw, acc2.w);
            acc3.x = fmaf(pv.w, hx, acc3.x); acc3.y = fmaf(pv.w, hy, acc3.y);
            acc3.z = fmaf(pv.w, hz, acc3.z); acc3.w = fmaf(pv.w, hw, acc3.w);
            dn0 += pv.x; dn1 += pv.y; dn2 += pv.z; dn3 += pv.w;
        }

        // ---- merge: rq-partials into OWN dead h region (no shuffles) ----
        *(float4*)&fregion[rq * 256 + 0 * 64 + dc * 4] = acc0;
        *(float4*)&fregion[rq * 256 + 1 * 64 + dc * 4] = acc1;
        *(float4*)&fregion[rq * 256 + 2 * 64 + dc * 4] = acc2;
        *(float4*)&fregion[rq * 256 + 3 * 64 + dc * 4] = acc3;
        if (dc == 0)
            *(float4*)&den_s[w][rq][0] = make_float4(dn0, dn1, dn2, dn3);
    }

    __syncthreads();

    // ---- epilogue: sum 16 partials (4 waves x 4 rq) per output element ----
    {
        const float* fb = (const float*)hbuf;
        float s = 0.f;
        #pragma unroll
        for (int i = 0; i < 16; ++i)
            s += fb[(i >> 2) * FREG + (i & 3) * 256 + t];  // stride-1 in t
        const int k = t >> 6;
        float den = 0.f;
        #pragma unroll
        for (int i = 0; i < 16; ++i)
            den += den_s[i >> 2][i & 3][k];                // broadcast reads
        out[(size_t)n * (KK * DD) + t] = s / den;          // den>0 (slen>=1)
    }
}

extern "C" void kernel_launch(void* const* d_in, const int* in_sizes, int n_in,
                              void* d_out, int out_size, void* d_ws, size_t ws_size,
                              hipStream_t stream) {
    const float* h_g  = (const float*)d_in[0];
    const int*   slen = (const int*)  d_in[1];
    const float* W1w  = (const float*)d_in[2];
    const float* W1b  = (const float*)d_in[3];
    const float* W2w  = (const float*)d_in[4];
    const float* W2b  = (const float*)d_in[5];
    float*       outp = (float*)d_out;

    const int N = in_sizes[1];

    mie_fused<<<dim3(N), dim3(256), 0, stream>>>(h_g, slen, W1w, W1b, W2w, W2b, outp);
}

// Round 9
// 58.845 us; speedup vs baseline: 2.2572x; 1.0341x over previous
//
#include <hip/hip_runtime.h>
#include <math.h>

// MultiInterestExtractor — round 9: blocked row->wave mapping + work ∝ slen.
// r8 post-mortem: score pass (largest phase: 16 ds_read_b64 + ~380 VALU) was
// FIXED-cost per wave while mean valid rows/wave = 25/52 — interleaved row
// assignment made every wave pay full capacity for masked rows. Blocked
// mapping (wave w: rows [50w,50w+50)) idles trailing waves for short samples
// (mean active 2.5/4), skipping their score+stage entirely; stage iterations
// now jmax = ceil(nrows/4) instead of fixed 13. LDS 30.2KB -> 5 blocks/CU
// (launch_bounds(256,5), ~70 VGPR). bf16-h staging, XOR-swizzled uint2 slots,
// fixed-shift softmax (e = exp(s - B_k), hard bound, tanh in [-1,1]),
// plain-sum merge in the wave's dead h region — all carried from r8.

#define LL 200
#define DD 64
#define AA 5
#define KK 4
#define RPW 50             // rows per wave (blocked)
#define WU2 832            // uint2 slots per wave region (52 rows x 16)
#define FREG (WU2 * 2)     // floats per region as merge scratch

__device__ __forceinline__ unsigned bf16_rne(float f) {   // finite inputs
    unsigned u = __float_as_uint(f);
    return (u + 0x7FFFu + ((u >> 16) & 1u)) >> 16;
}
__device__ __forceinline__ unsigned pk2(float lo, float hi) {
    return bf16_rne(lo) | (bf16_rne(hi) << 16);
}
__device__ __forceinline__ float lo16(unsigned u) { return __uint_as_float(u << 16); }
__device__ __forceinline__ float hi16(unsigned u) { return __uint_as_float(u & 0xFFFF0000u); }

__device__ __forceinline__ float fast_tanh(float x) {
    float e = __expf(2.f * x);                          // +inf for large x ok
    return 1.f - 2.f * __builtin_amdgcn_rcpf(e + 1.f);  // saturates to +/-1
}

__global__ __launch_bounds__(256, 5)
void mie_fused(const float* __restrict__ h_g,    // [N, L, D]
               const int*   __restrict__ slen_g, // [N]
               const float* __restrict__ W1w,    // [A, D]
               const float* __restrict__ W1b,    // [A]
               const float* __restrict__ W2w,    // [K, A]
               const float* __restrict__ W2b,    // [K]
               float*       __restrict__ out)    // [N, K, D]
{
    __shared__ uint2  hbuf[4 * WU2];        // 26624 B (bf16 h, 4 wave regions)
    __shared__ float4 p4s[4][52];           //  3328 B per-row e[k]
    __shared__ float  den_s[4][4][KK];      //   256 B [wave][rq][k]

    const int n    = blockIdx.x;
    const int t    = threadIdx.x;
    const int w    = t >> 6;                // wave id
    const int lane = t & 63;
    const int slen = slen_g[n];

    // blocked assignment: wave w owns global rows [RPW*w, RPW*w + nrows)
    const int nrows = min(max(slen - w * RPW, 0), RPW);   // 0..50
    uint2* hbw     = &hbuf[w * WU2];
    float* fregion = (float*)hbw;           // merge scratch (h dead by then)

    if (nrows == 0) {
        // idle wave (mean 1.5 of 4): zero merge region + den, wait at barrier
        float4 z = {0.f, 0.f, 0.f, 0.f};
        #pragma unroll
        for (int q = 0; q < 4; ++q)
            *(float4*)&fregion[q * 256 + lane * 4] = z;
        if (lane < 4) *(float4*)&den_s[w][lane][0] = z;
    } else {
        const int nf4  = slen * 16;
        const float4* hn4 = (const float4*)(h_g + (size_t)n * (LL * DD));
        const int base = w * RPW * 16;              // first f4 of wave's span
        const int jmax = (nrows + 3) >> 2;          // 1..13 stage/PV groups

        // ---- stage: groups of 4 slots-of-64 (prefetch depth 4, 16 VGPR);
        //      each instr reads a contiguous 1KB; pack bf16, XOR swizzle ----
        for (int j0 = 0; j0 < jmax; j0 += 4) {
            float4 rn[4];
            #pragma unroll
            for (int u = 0; u < 4; ++u) {
                int i = (j0 + u) * 64 + lane;
                rn[u] = hn4[min(base + i, nf4 - 1)];   // clamp: L2 dup, finite
            }
            #pragma unroll
            for (int u = 0; u < 4; ++u) {
                int j = j0 + u;
                if (j < jmax) {
                    int i = j * 64 + lane;
                    int r = i >> 4, c = i & 15;        // r <= 51
                    hbw[r * 16 + (c ^ (r & 15))] =
                        make_uint2(pk2(rn[u].x, rn[u].y), pk2(rn[u].z, rn[u].w));
                }
            }
        }

        // hard per-head score bound (tanh in [-1,1]): same shift everywhere
        float Bk[KK];
        #pragma unroll
        for (int k = 0; k < KK; ++k) {
            float b = fabsf(W2b[k]);
            #pragma unroll
            for (int a = 0; a < AA; ++a) b += fabsf(W2w[k * AA + a]);
            Bk[k] = b;
        }

        asm volatile("s_waitcnt lgkmcnt(0)" ::: "memory");

        // ---- scores: lane = local row (dup-clamped to valid -> finite,
        //      broadcast reads free); W1 lane-uniform -> scalar loads ----
        const float4* W14 = (const float4*)W1w;
        const int rl = min(lane, nrows - 1);
        float a0 = W1b[0], a1 = W1b[1], a2 = W1b[2], a3 = W1b[3], a4 = W1b[4];
        #pragma unroll
        for (int i = 0; i < 16; ++i) {
            uint2 q = hbw[rl * 16 + (i ^ (rl & 15))];
            float hx = lo16(q.x), hy = hi16(q.x), hz = lo16(q.y), hw = hi16(q.y);
            float4 w0 = W14[0*16+i], w1 = W14[1*16+i], w2 = W14[2*16+i],
                   w3 = W14[3*16+i], w4 = W14[4*16+i];
            a0 = fmaf(hx, w0.x, fmaf(hy, w0.y, fmaf(hz, w0.z, fmaf(hw, w0.w, a0))));
            a1 = fmaf(hx, w1.x, fmaf(hy, w1.y, fmaf(hz, w1.z, fmaf(hw, w1.w, a1))));
            a2 = fmaf(hx, w2.x, fmaf(hy, w2.y, fmaf(hz, w2.z, fmaf(hw, w2.w, a2))));
            a3 = fmaf(hx, w3.x, fmaf(hy, w3.y, fmaf(hz, w3.z, fmaf(hw, w3.w, a3))));
            a4 = fmaf(hx, w4.x, fmaf(hy, w4.y, fmaf(hz, w4.z, fmaf(hw, w4.w, a4))));
        }
        const bool vrow = lane < nrows;
        const float t0 = fast_tanh(a0), t1 = fast_tanh(a1), t2 = fast_tanh(a2),
                    t3 = fast_tanh(a3), t4 = fast_tanh(a4);
        float e[KK];
        #pragma unroll
        for (int k = 0; k < KK; ++k) {
            float s = W2b[k];
            s = fmaf(t0, W2w[k*AA+0], s);
            s = fmaf(t1, W2w[k*AA+1], s);
            s = fmaf(t2, W2w[k*AA+2], s);
            s = fmaf(t3, W2w[k*AA+3], s);
            s = fmaf(t4, W2w[k*AA+4], s);
            e[k] = vrow ? __expf(s - Bk[k]) : 0.f;         // e in (0,1]
        }
        if (lane < 52)
            p4s[w][lane] = make_float4(e[0], e[1], e[2], e[3]); // pads: e=0

        asm volatile("s_waitcnt lgkmcnt(0)" ::: "memory");

        // ---- PV: lane = (rq = lane>>4 row-in-group, dc = lane&15 slot) ----
        const int rq = lane >> 4, dc = lane & 15;
        float4 acc0 = {0,0,0,0}, acc1 = {0,0,0,0}, acc2 = {0,0,0,0}, acc3 = {0,0,0,0};
        float dn0 = 0.f, dn1 = 0.f, dn2 = 0.f, dn3 = 0.f;
        for (int g = 0; g < jmax; ++g) {
            const int row = g * 4 + rq;                    // <= 51; pads e=0
            uint2 q = hbw[row * 16 + (dc ^ (row & 15))];
            float hx = lo16(q.x), hy = hi16(q.x), hz = lo16(q.y), hw = hi16(q.y);
            float4 pv = p4s[w][row];
            acc0.x = fmaf(pv.x, hx, acc0.x); acc0.y = fmaf(pv.x, hy, acc0.y);
            acc0.z = fmaf(pv.x, hz, acc0.z); acc0.w = fmaf(pv.x, hw, acc0.w);
            acc1.x = fmaf(pv.y, hx, acc1.x); acc1.y = fmaf(pv.y, hy, acc1.y);
            acc1.z = fmaf(pv.y, hz, acc1.z); acc1.w = fmaf(pv.y, hw, acc1.w);
            acc2.x = fmaf(pv.z, hx, acc2.x); acc2.y = fmaf(pv.z, hy, acc2.y);
            acc2.z = fmaf(pv.z, hz, acc2.z); acc2.w = fmaf(pv.z, hw, acc2.w);
            acc3.x = fmaf(pv.w, hx, acc3.x); acc3.y = fmaf(pv.w, hy, acc3.y);
            acc3.z = fmaf(pv.w, hz, acc3.z); acc3.w = fmaf(pv.w, hw, acc3.w);
            dn0 += pv.x; dn1 += pv.y; dn2 += pv.z; dn3 += pv.w;
        }

        // ---- merge: rq-partials into OWN dead h region (no shuffles) ----
        *(float4*)&fregion[rq * 256 + 0 * 64 + dc * 4] = acc0;
        *(float4*)&fregion[rq * 256 + 1 * 64 + dc * 4] = acc1;
        *(float4*)&fregion[rq * 256 + 2 * 64 + dc * 4] = acc2;
        *(float4*)&fregion[rq * 256 + 3 * 64 + dc * 4] = acc3;
        if (dc == 0)
            *(float4*)&den_s[w][rq][0] = make_float4(dn0, dn1, dn2, dn3);
    }

    __syncthreads();

    // ---- epilogue: sum 16 partials (4 waves x 4 rq) per output element ----
    {
        const float* fb = (const float*)hbuf;
        float s = 0.f;
        #pragma unroll
        for (int i = 0; i < 16; ++i)
            s += fb[(i >> 2) * FREG + (i & 3) * 256 + t];  // stride-1 in t
        const int k = t >> 6;
        float den = 0.f;
        #pragma unroll
        for (int i = 0; i < 16; ++i)
            den += den_s[i >> 2][i & 3][k];                // broadcast reads
        out[(size_t)n * (KK * DD) + t] = s / den;          // den>0 (slen>=1)
    }
}

extern "C" void kernel_launch(void* const* d_in, const int* in_sizes, int n_in,
                              void* d_out, int out_size, void* d_ws, size_t ws_size,
                              hipStream_t stream) {
    const float* h_g  = (const float*)d_in[0];
    const int*   slen = (const int*)  d_in[1];
    const float* W1w  = (const float*)d_in[2];
    const float* W1b  = (const float*)d_in[3];
    const float* W2w  = (const float*)d_in[4];
    const float* W2b  = (const float*)d_in[5];
    float*       outp = (float*)d_out;

    const int N = in_sizes[1];

    mie_fused<<<dim3(N), dim3(256), 0, stream>>>(h_g, slen, W1w, W1b, W2w, W2b, outp);
}